// Round 12
// baseline (368.386 us; speedup 1.0000x reference)
//
#include <hip/hip_runtime.h>
#include <cstdint>
#include <cstddef>

#define NEG_SLOPE 0.2f
#define BIN_SHIFT 7      // 128 nodes per bucket -> K=782 scatter blocks (3/CU TLP)
#define BCAP 4096        // per-bucket capacity (expected ~2176, +41 sigma)
#define LOG2E 1.4426950408889634f

typedef short bf16x8 __attribute__((ext_vector_type(8)));
typedef float f32x4 __attribute__((ext_vector_type(4)));

#if __has_builtin(__builtin_amdgcn_exp2f)
#define EXP2(x) __builtin_amdgcn_exp2f(x)
#else
#define EXP2(x) exp2f(x)
#endif

// fp32 -> bf16 RTNE
static __device__ __forceinline__ unsigned short bf16r(float f) {
    unsigned u = __float_as_uint(f);
    return (unsigned short)((u + 0x7fffu + ((u >> 16) & 1u)) >> 16);
}
static __device__ __forceinline__ float bfu_lo(unsigned u) { return __uint_as_float(u << 16); }
static __device__ __forceinline__ float bfu_hi(unsigned u) { return __uint_as_float(u & 0xffff0000u); }

// ---------------- W prep: bf16 hi/lo split into MFMA-fragment-contiguous layout + bcnt zero ----------------
__global__ __launch_bounds__(256) void wprep_k(const float* __restrict__ W1, const float* __restrict__ W2,
                                               unsigned short* __restrict__ Wh1, unsigned short* __restrict__ Wl1,
                                               unsigned short* __restrict__ Wh2, unsigned short* __restrict__ Wl2,
                                               int* __restrict__ bcnt) {
    if (blockIdx.x < 4) bcnt[blockIdx.x * 256 + threadIdx.x] = 0;   // 1024 bucket counters
    int t = blockIdx.x * 256 + threadIdx.x;       // grid 128 -> 32768 threads
    const float* W;
    unsigned short *Wh, *Wl;
    int idx;
    if (t < 16384) { W = W1; Wh = Wh1; Wl = Wl1; idx = t; }
    else           { W = W2; Wh = Wh2; Wl = Wl2; idx = t - 16384; }
    int c = idx >> 7;     // output col 0..127
    int k = idx & 127;    // input k 0..127
    float w = W[(size_t)k * 128 + c];
    unsigned short h = bf16r(w);
    float lo = w - __uint_as_float((unsigned)h << 16);
    int dst = (k >> 5) * 4096 + (c >> 4) * 512 + (((k >> 3) & 3) * 16 + (c & 15)) * 8 + (k & 7);
    Wh[dst] = h;
    Wl[dst] = bf16r(lo);
}

// ---------------- Phase A: bin edges into fixed-capacity dst buckets (int4 loads, direct writes) ----------------
// tmpE entry packed: (src << 7) | (dst & 127). Staging dropped (R8 A/B: neutral); 3 barriers, 8KB LDS.
__global__ __launch_bounds__(256) void bin_k(const int* __restrict__ srcI, const int* __restrict__ dstI,
                                             int E, int N, int K, int* __restrict__ bcnt,
                                             int* __restrict__ tmpE) {
    __shared__ int hist[1024];
    __shared__ int lbase[1024];
    const int t = threadIdx.x;
    const int M = E + N;
    const int chunk0 = blockIdx.x * 4096;
#pragma unroll
    for (int j = 0; j < 4; ++j) hist[t + j * 256] = 0;
    __syncthreads();

    int pk[16], bk[16];
#pragma unroll
    for (int jj = 0; jj < 4; ++jj) {
        int ebase = chunk0 + (t + jj * 256) * 4;
        if (ebase + 4 <= E) {
            int4 s4 = *(const int4*)&srcI[ebase];
            int4 d4 = *(const int4*)&dstI[ebase];
            int ssv[4] = {s4.x, s4.y, s4.z, s4.w};
            int ddv[4] = {d4.x, d4.y, d4.z, d4.w};
#pragma unroll
            for (int j = 0; j < 4; ++j) {
                int q = jj * 4 + j;
                bk[q] = -1;
                if ((unsigned)ddv[j] < (unsigned)N && (unsigned)ssv[j] < (unsigned)N) {
                    bk[q] = ddv[j] >> BIN_SHIFT;
                    pk[q] = (ssv[j] << BIN_SHIFT) | (ddv[j] & 127);
                    atomicAdd(&hist[bk[q]], 1);
                }
            }
        } else {
#pragma unroll
            for (int j = 0; j < 4; ++j) {
                int q = jj * 4 + j;
                int i = ebase + j;
                bk[q] = -1;
                if (i < M) {
                    int ss, dd;
                    if (i < E) { ss = srcI[i]; dd = dstI[i]; }
                    else       { ss = i - E;  dd = ss; }          // self-loops
                    if ((unsigned)dd < (unsigned)N && (unsigned)ss < (unsigned)N) {
                        bk[q] = dd >> BIN_SHIFT;
                        pk[q] = (ss << BIN_SHIFT) | (dd & 127);
                        atomicAdd(&hist[bk[q]], 1);
                    }
                }
            }
        }
    }
    __syncthreads();
#pragma unroll
    for (int j = 0; j < 4; ++j) {
        int b = t + j * 256;
        if (b < K) {
            int h = hist[b];
            lbase[b] = (h > 0) ? atomicAdd(&bcnt[b], h) : 0;
            hist[b] = 0;   // reuse as placement cursor (owner-write before barrier)
        }
    }
    __syncthreads();
#pragma unroll
    for (int j = 0; j < 16; ++j) {
        if (bk[j] >= 0) {
            int r = atomicAdd(&hist[bk[j]], 1);
            int pos = lbase[bk[j]] + r;
            if (pos < BCAP) tmpE[(size_t)bk[j] * BCAP + pos] = pk[j];
        }
    }
}

// ---------------- Phase B: per-bucket local CSR build + scatter; colOff = src*256 (byte offset) ----------------
// K=782 blocks (3/CU); per-block passes ~3 int4 iterations; 128-entry node scan.
__global__ __launch_bounds__(256) void scatter_csr_k(const int* __restrict__ tmpE,
                                                     const int* __restrict__ bcnt,
                                                     int* __restrict__ rowptr,
                                                     int* __restrict__ colOff,
                                                     int N, int K) {
    __shared__ int tl[256];
    __shared__ int allB[1025];
    __shared__ int cur[128];
    __shared__ int sc[128];
    const int t = threadIdx.x;
    const int b = blockIdx.x;

    // bucket-base scan over K (padded to 1024): 4 elems per thread + 256-scan
    int v[4];
    int run = 0;
#pragma unroll
    for (int j = 0; j < 4; ++j) {
        int idx = 4 * t + j;
        int x = (idx < K) ? min(bcnt[idx], BCAP) : 0;
        v[j] = run;
        run += x;
    }
    tl[t] = run;
    __syncthreads();
    for (int off = 1; off < 256; off <<= 1) {
        int u = (t >= off) ? tl[t - off] : 0;
        __syncthreads();
        tl[t] += u;
        __syncthreads();
    }
    int excl = (t == 0) ? 0 : tl[t - 1];
#pragma unroll
    for (int j = 0; j < 4; ++j) allB[4 * t + j] = excl + v[j];
    if (t == 255) allB[1024] = tl[255];
    __syncthreads();

    const int base_b = allB[b];
    const int cnt_b  = allB[b + 1] - base_b;
    if (b == K - 1 && t == 0) rowptr[N] = allB[K];

    const int nlo = b << BIN_SHIFT;
    const int nhi = min(nlo + (1 << BIN_SHIFT), N);
    const int nn  = nhi - nlo;
    const int* te = tmpE + (size_t)b * BCAP;   // 16KB slab: int4 reads stay in-bounds

    if (t < 128) cur[t] = 0;
    __syncthreads();
    for (int i0 = t * 4; i0 < cnt_b; i0 += 1024) {
        int4 vv = *(const int4*)&te[i0];
        int a[4] = {vv.x, vv.y, vv.z, vv.w};
#pragma unroll
        for (int j = 0; j < 4; ++j)
            if (i0 + j < cnt_b) atomicAdd(&cur[a[j] & 127], 1);
    }
    __syncthreads();

    // exclusive scan over the 128 node counts (threads t<128 active)
    if (t < 128) sc[t] = cur[t];
    __syncthreads();
    for (int off = 1; off < 128; off <<= 1) {
        int u = (t >= off && t < 128) ? sc[t - off] : 0;
        __syncthreads();
        if (t < 128) sc[t] += u;
        __syncthreads();
    }
    if (t < 128) {
        int e0 = (t == 0) ? 0 : sc[t - 1];
        if (t < nn) rowptr[nlo + t] = base_b + e0;
        cur[t] = e0;   // cursor
    }
    __syncthreads();

    for (int i0 = t * 4; i0 < cnt_b; i0 += 1024) {
        int4 vv = *(const int4*)&te[i0];
        int a[4] = {vv.x, vv.y, vv.z, vv.w};
#pragma unroll
        for (int j = 0; j < 4; ++j) {
            if (i0 + j < cnt_b) {
                int r = atomicAdd(&cur[a[j] & 127], 1);
                colOff[base_b + r] = ((unsigned)a[j] >> BIN_SHIFT) << 8;   // src's 256B Hbuf row
            }
        }
    }
}

// ---------------- h = X @ W via split-bf16 MFMA; bf16 Hout + log2e-scaled fp32 alphas ----------------
// X@W ~= Xh@Wh + Xl@Wh + Xh@Wl (dropped Xl@Wl ~2^-18) -> fp32-grade accuracy.
__global__ __launch_bounds__(256) void gemm_mfma_k(const float* __restrict__ X,
                                                   const unsigned short* __restrict__ Wh,
                                                   const unsigned short* __restrict__ Wl,
                                                   const float* __restrict__ a_s,
                                                   const float* __restrict__ a_d,
                                                   unsigned short* __restrict__ Hout,
                                                   float* __restrict__ asrc,
                                                   float* __restrict__ adst,
                                                   int N) {
    __shared__ __align__(16) unsigned short hstage[4][32][132];  // +4 pad: conflict-light
    const int tid = threadIdx.x;
    const int wid = tid >> 6;
    const int l   = tid & 63;
    const int l15 = l & 15;
    const int lh  = l >> 4;
    const int waveRow = blockIdx.x * 128 + wid * 32;
    if (waveRow >= N) return;

    f32x4 acc[2][8];
#pragma unroll
    for (int m = 0; m < 2; ++m)
#pragma unroll
        for (int f = 0; f < 8; ++f)
#pragma unroll
            for (int c = 0; c < 4; ++c) acc[m][f][c] = 0.f;

    const int r0 = waveRow + l15;
    const int r1 = waveRow + 16 + l15;
    const size_t xoff0 = (size_t)min(r0, N - 1) * 128;   // clamp: junk rows never stored
    const size_t xoff1 = (size_t)min(r1, N - 1) * 128;
    const int kb = lh * 8;

#pragma unroll
    for (int ks = 0; ks < 4; ++ks) {
        bf16x8 ah[2], al[2];
#pragma unroll
        for (int m = 0; m < 2; ++m) {
            const float* xp = X + (m ? xoff1 : xoff0) + ks * 32 + kb;
            float4 v0 = *(const float4*)xp;
            float4 v1 = *(const float4*)(xp + 4);
            float xs[8] = {v0.x, v0.y, v0.z, v0.w, v1.x, v1.y, v1.z, v1.w};
#pragma unroll
            for (int j = 0; j < 8; ++j) {
                unsigned short h = bf16r(xs[j]);
                float hf = __uint_as_float((unsigned)h << 16);
                ah[m][j] = (short)h;
                al[m][j] = (short)bf16r(xs[j] - hf);
            }
        }
        const unsigned short* wbh = Wh + ks * 4096 + l * 8;
        const unsigned short* wbl = Wl + ks * 4096 + l * 8;
#pragma unroll
        for (int f = 0; f < 8; ++f) {
            bf16x8 wh = *(const bf16x8*)(wbh + f * 512);
            bf16x8 wl = *(const bf16x8*)(wbl + f * 512);
#pragma unroll
            for (int m = 0; m < 2; ++m) {
                acc[m][f] = __builtin_amdgcn_mfma_f32_16x16x32_bf16(ah[m], wh, acc[m][f], 0, 0, 0);
                acc[m][f] = __builtin_amdgcn_mfma_f32_16x16x32_bf16(al[m], wh, acc[m][f], 0, 0, 0);
                acc[m][f] = __builtin_amdgcn_mfma_f32_16x16x32_bf16(ah[m], wl, acc[m][f], 0, 0, 0);
            }
        }
    }

    float asf[8], adf[8];
#pragma unroll
    for (int f = 0; f < 8; ++f) {
        asf[f] = a_s[f * 16 + l15];
        adf[f] = a_d[f * 16 + l15];
    }
    const int q = l15;
#pragma unroll
    for (int m = 0; m < 2; ++m) {
#pragma unroll
        for (int r = 0; r < 4; ++r) {
            float ps[4] = {0.f, 0.f, 0.f, 0.f};
            float pd[4] = {0.f, 0.f, 0.f, 0.f};
#pragma unroll
            for (int f = 0; f < 8; ++f) {
                float v = acc[m][f][r];
                ps[f >> 1] = fmaf(v, asf[f], ps[f >> 1]);
                pd[f >> 1] = fmaf(v, adf[f], pd[f >> 1]);
                hstage[wid][m * 16 + lh * 4 + r][f * 16 + l15] = bf16r(v);
            }
#pragma unroll
            for (int mask = 1; mask < 16; mask <<= 1) {
#pragma unroll
                for (int h = 0; h < 4; ++h) {
                    ps[h] += __shfl_xor(ps[h], mask);
                    pd[h] += __shfl_xor(pd[h], mask);
                }
            }
            int row = waveRow + m * 16 + lh * 4 + r;
            if (q < 8 && row < N) {
                float v0 = (q & 1) ? ps[1] : ps[0];
                float v1 = (q & 1) ? ps[3] : ps[2];
                float vs = (q & 2) ? v1 : v0;
                float w0 = (q & 1) ? pd[1] : pd[0];
                float w1 = (q & 1) ? pd[3] : pd[2];
                float vd = (q & 2) ? w1 : w0;
                // pre-scale by log2(e): aggregate uses native exp2 (lrelu is pos-homogeneous)
                if (q < 4) asrc[row * 4 + q] = vs * LOG2E;
                else       adst[row * 4 + (q - 4)] = vd * LOG2E;
            }
        }
    }

    // coalesced bf16 store: 16 lanes cover one 256B h-row, 4 rows per iteration
#pragma unroll
    for (int it = 0; it < 8; ++it) {
        int row = it * 4 + lh;
        const unsigned short* hp = &hstage[wid][row][l15 * 8];
        uint2 aa = *(const uint2*)hp;
        uint2 bb = *(const uint2*)(hp + 4);
        int grow = waveRow + row;
        if (grow < N) {
            uint4 o;
            o.x = aa.x; o.y = aa.y; o.z = bb.x; o.w = bb.y;
            *(uint4*)&Hout[(size_t)grow * 128 + l15 * 8] = o;
        }
    }
}

// ---------------- aggregation: one wave per dst node; all-8-wide predicated chunks (no serial tail) ----------------
// w = exp2(lrelu(asrc'+adst')) with alphas pre-scaled by log2e == exp(lrelu(asrc+adst)).
__global__ __launch_bounds__(256) void aggregate_k(const unsigned short* __restrict__ Hbuf,
                                                   const float* __restrict__ asrc,
                                                   const float* __restrict__ adst,
                                                   const int* __restrict__ rowptr,
                                                   const int* __restrict__ colOff,
                                                   const float* __restrict__ bias,
                                                   float* __restrict__ out, int N) {
    int wave = (blockIdx.x * 256 + threadIdx.x) >> 6;
    int lane = threadIdx.x & 63;
    if (wave >= N) return;
    const int n = wave;
    const int c0 = lane * 2;
    const int head = c0 >> 5;
    const float adh = adst[n * 4 + head];
    const char* Hb = (const char*)Hbuf;
    const char* As = (const char*)asrc;
    const int hoff = c0 * 2;            // byte offset of this lane's h dword in a 256B row
    const int aoff = head * 4;

    int b = __builtin_amdgcn_readfirstlane(rowptr[n]);
    int e = __builtin_amdgcn_readfirstlane(rowptr[n + 1]);
    float acc0 = 0.f, acc1 = 0.f, sw = 0.f;
    for (int p = b; p < e; p += 8) {
        int off[8];
#pragma unroll
        for (int j = 0; j < 8; ++j) off[j] = colOff[min(p + j, e - 1)];
        float a[8];
#pragma unroll
        for (int j = 0; j < 8; ++j) a[j] = *(const float*)(As + (off[j] >> 4) + aoff);
        unsigned hu[8];
#pragma unroll
        for (int j = 0; j < 8; ++j) hu[j] = *(const unsigned*)(Hb + off[j] + hoff);
#pragma unroll
        for (int j = 0; j < 8; ++j) {
            float x = a[j] + adh;
            float w = (p + j < e) ? EXP2(fmaxf(x, NEG_SLOPE * x)) : 0.f;
            sw += w;
            acc0 = fmaf(w, bfu_lo(hu[j]), acc0);
            acc1 = fmaf(w, bfu_hi(hu[j]), acc1);
        }
    }
    float inv = 1.f / sw;
    float o0 = fmaxf(acc0 * inv + bias[c0], 0.f);
    float o1 = fmaxf(acc1 * inv + bias[c0 + 1], 0.f);
    *(float2*)&out[(size_t)n * 128 + c0] = make_float2(o0, o1);
}

// ---------------- launch: 7 dispatches ----------------

extern "C" void kernel_launch(void* const* d_in, const int* in_sizes, int n_in,
                              void* d_out, int out_size, void* d_ws, size_t ws_size,
                              hipStream_t stream) {
    const float* X   = (const float*)d_in[0];
    const int*   EI  = (const int*)d_in[1];
    const float* W1  = (const float*)d_in[2];
    const float* as1 = (const float*)d_in[3];
    const float* ad1 = (const float*)d_in[4];
    const float* b1  = (const float*)d_in[5];
    const float* W2  = (const float*)d_in[6];
    const float* as2 = (const float*)d_in[7];
    const float* ad2 = (const float*)d_in[8];
    const float* b2  = (const float*)d_in[9];

    const int N = in_sizes[0] / 128;
    const int E = in_sizes[1] / 2;
    const int M = E + N;
    const int K = (N + (1 << BIN_SHIFT) - 1) >> BIN_SHIFT;   // <= 1024 for N <= 131072
    const int* srcI = EI;
    const int* dstI = EI + E;

    char* w = (char*)d_ws;
    auto alloc = [&](size_t bytes) {
        char* p = w;
        w += (bytes + 255) & ~(size_t)255;
        return p;
    };
    unsigned short* Hbuf = (unsigned short*)alloc((size_t)N * 128 * 2);  // bf16, 256B rows
    float* asrc   = (float*)alloc((size_t)N * 4 * 4);
    float* adst   = (float*)alloc((size_t)N * 4 * 4);
    int*   rowptr = (int*)alloc((size_t)(N + 1) * 4);
    int*   colOff = (int*)alloc((size_t)M * 4);
    int*   tmpE   = (int*)alloc((size_t)K * BCAP * 4);       // packed (src<<7 | dst&127)
    int*   bcnt   = (int*)alloc(1024 * 4);
    unsigned short* Wt1h = (unsigned short*)alloc(128 * 128 * 2);
    unsigned short* Wt1l = (unsigned short*)alloc(128 * 128 * 2);
    unsigned short* Wt2h = (unsigned short*)alloc(128 * 128 * 2);
    unsigned short* Wt2l = (unsigned short*)alloc(128 * 128 * 2);

    const int gemmBlocks = (N + 127) / 128;
    float* out = (float*)d_out;

    // 1: W pre-split (fragment-contiguous layout) + bcnt zeroing
    wprep_k<<<128, 256, 0, stream>>>(W1, W2, Wt1h, Wt1l, Wt2h, Wt2l, bcnt);
    // 2: bin edges into buckets (int4 loads, direct writes, 3 barriers)
    bin_k<<<(M + 4095) / 4096, 256, 0, stream>>>(srcI, dstI, E, N, K, bcnt, tmpE);
    // 3: per-bucket CSR build + scatter (782 blocks = 3/CU TLP)
    scatter_csr_k<<<K, 256, 0, stream>>>(tmpE, bcnt, rowptr, colOff, N, K);
    // 4: gemm layer 1 (activation staged in d_out, fp32)
    gemm_mfma_k<<<gemmBlocks, 256, 0, stream>>>(X, Wt1h, Wt1l, as1, ad1, Hbuf, asrc, adst, N);
    // 5: aggregate layer 1
    aggregate_k<<<((size_t)N * 64 + 255) / 256, 256, 0, stream>>>(Hbuf, asrc, adst, rowptr, colOff, b1, out, N);
    // 6: gemm layer 2
    gemm_mfma_k<<<gemmBlocks, 256, 0, stream>>>(out, Wt2h, Wt2l, as2, ad2, Hbuf, asrc, adst, N);
    // 7: aggregate layer 2
    aggregate_k<<<((size_t)N * 64 + 255) / 256, 256, 0, stream>>>(Hbuf, asrc, adst, rowptr, colOff, b2, out, N);
}